// Round 2
// baseline (122.954 us; speedup 1.0000x reference)
//
#include <hip/hip_runtime.h>
#include <stdint.h>

// NeuSDF round 11 (= r10 with compile fix). Verified world: inputs f32,
// output f32, bf16-space compare (floor 0.002, threshold 0.0134).
// out = tanh(s(F)), s tabulated (NT=16384).
// r9: 117.6us; main is gather-bound: 7 scattered loads/pt (6 plane + 1
// table). r10/r11: QUAD-PACK the 2x2 bilinear footprint into one 8B uint2
// (4 bf16) -> 1 gather/plane, 4 gathers/pt total (-43%). Numerics identical
// to r9 (same bf16 values + clamping). vp grows 3->6 MB. Nontemporal point
// loads / out stores (via ext_vector_type -- HIP_vector_type rejected by the
// builtin) keep vp L2-resident.

#define NT      16384
#define F_LO    (-20.0f)
#define F_DELTA (40.0f / (float)NT)
#define F_INVD  ((float)NT / 40.0f)

#define PLANE_ELEMS (512 * 512)
#define VP_BYTES    ((size_t)(3 * PLANE_ELEMS) * 8)   // 6 MB (quad-packed)
#define TP_OFF      VP_BYTES
#define WS_NEED     (TP_OFF + (size_t)NT * 8)

#define PACK_BLOCKS  (3 * PLANE_ELEMS / 1024)         // 768
#define BUILD_BLOCKS ((NT - 1 + 62) / 63)             // 261

typedef float f32x4 __attribute__((ext_vector_type(4)));

__device__ __forceinline__ uint32_t f2bfbits(float f) {  // RNE
  union { float f; uint32_t i; } x; x.f = f;
  uint32_t r = x.i + 0x7fffu + ((x.i >> 16) & 1u);
  return r >> 16;
}
__device__ __forceinline__ float asf(uint32_t u) {
  union { uint32_t i; float f; } x; x.i = u; return x.f;
}

// ---------------- tier1 prep: pack (blocks [0,768)) + build (rest) ----------
__global__ __launch_bounds__(1024) void neusdf_prep(
    const float* __restrict__ xy, const float* __restrict__ yz,
    const float* __restrict__ xz,
    const float* __restrict__ w1, const float* __restrict__ b1,
    const float* __restrict__ w2, const float* __restrict__ b2,
    const float* __restrict__ w3, const float* __restrict__ b3,
    uint2* __restrict__ vp, float2* __restrict__ tp) {
  __shared__ float part[16][64];
  __shared__ float tv[64];
  const int tid = threadIdx.x;

  if (blockIdx.x < PACK_BLOCKS) {
    // ---- pack planes as 2x2 bf16 quads:
    // vp[pl][r*512+c] = { bf16(p[r][c]) | bf16(p[r1][c])<<16,
    //                     bf16(p[r][c1]) | bf16(p[r1][c1])<<16 }
    // r1 = min(r+1,511), c1 = min(c+1,511)  (same clamping main used in r9)
    const int idx = blockIdx.x * 1024 + tid;
    const int pl = idx >> 18;
    const int rc = idx & (PLANE_ELEMS - 1);
    const int r = rc >> 9, c = rc & 511;
    const float* p = (pl == 0) ? xy : ((pl == 1) ? xz : yz);
    const int r1 = r + 1 > 511 ? 511 : r + 1;
    const int c1 = c + 1 > 511 ? 511 : c + 1;
    const uint32_t lo = f2bfbits(p[r  * 512 + c ]) | (f2bfbits(p[r1 * 512 + c ]) << 16);
    const uint32_t hi = f2bfbits(p[r  * 512 + c1]) | (f2bfbits(p[r1 * 512 + c1]) << 16);
    vp[idx] = make_uint2(lo, hi);
    return;
  }

  // ---- table build: 63 entries/block (overlapped so pairs are local),
  // 16 waves x 8 j-chains. h fused into k-loop (no h[] array -> no spill);
  // w2 rows via SGPR base -> s_load broadcast.
  const int lane = tid & 63, wave = tid >> 6;
  const int base = (blockIdx.x - PACK_BLOCKS) * 63;
  int entry = base + lane;
  if (entry > NT - 1) entry = NT - 1;
  const float F = F_LO + (float)entry * F_DELTA;
  const int j0 = __builtin_amdgcn_readfirstlane(wave * 8);

  float a[8];
  #pragma unroll
  for (int jj = 0; jj < 8; ++jj) a[jj] = b2[j0 + jj];
  #pragma unroll 8
  for (int k = 0; k < 128; ++k) {
    const float hk = fmaxf(fmaf(F, w1[k], b1[k]), 0.f);
    const float* wrow = &w2[k * 128 + j0];
    #pragma unroll
    for (int jj = 0; jj < 8; ++jj)
      a[jj] = fmaf(hk, wrow[jj], a[jj]);
  }
  float p = 0.f;
  #pragma unroll
  for (int jj = 0; jj < 8; ++jj)
    p = fmaf(fmaxf(a[jj], 0.f), w3[j0 + jj], p);
  part[wave][lane] = p;
  __syncthreads();

  if (tid < 64) {
    float s = b3[0];
    #pragma unroll
    for (int w = 0; w < 16; ++w) s += part[w][tid];
    const float e = exp2f(s * 2.885390081777927f);
    tv[tid] = 1.f - 2.f / (e + 1.f);          // tanh(s)
  }
  __syncthreads();
  if (tid < 63) {
    const int pi = base + tid;
    if (pi <= NT - 2) tp[pi] = make_float2(tv[tid], tv[tid + 1]);
  }
}

// ---------------- tier1 main: 4 pts/thread, 16 gathers in flight ------------
__global__ __launch_bounds__(256) void NeuSDF_1743756722497_kernel(
    const float* __restrict__ points,
    const uint2* __restrict__ vp,      // 2x2 bf16 quad planes: xy, xz, yz
    const float2* __restrict__ tp,     // tanh pairs
    float* __restrict__ out, int n) {
  const int t = blockIdx.x * 256 + threadIdx.x;
  const int i0 = t * 4;
  if (i0 >= n) return;

  float xs[4], ys[4], zs[4];
  if (i0 + 3 < n) {
    const f32x4* p4 = (const f32x4*)(points + (size_t)i0 * 3);  // 16B aligned
    const f32x4 a = __builtin_nontemporal_load(p4 + 0);
    const f32x4 b = __builtin_nontemporal_load(p4 + 1);
    const f32x4 c = __builtin_nontemporal_load(p4 + 2);
    xs[0] = a.x; ys[0] = a.y; zs[0] = a.z;
    xs[1] = a.w; ys[1] = b.x; zs[1] = b.y;
    xs[2] = b.z; ys[2] = b.w; zs[2] = c.x;
    xs[3] = c.y; ys[3] = c.z; zs[3] = c.w;
  } else {
    #pragma unroll
    for (int s = 0; s < 4; ++s) {
      const int i = i0 + s < n ? i0 + s : n - 1;
      xs[s] = points[3 * i + 0]; ys[s] = points[3 * i + 1]; zs[s] = points[3 * i + 2];
    }
  }

  float res[4];
  #pragma unroll
  for (int s = 0; s < 4; ++s) {
    const float px = (xs[s] + 1.f) * 0.5f * 511.f;
    const float py = (ys[s] + 1.f) * 0.5f * 511.f;
    const float pz = (zs[s] + 1.f) * 0.5f * 511.f;

    float F = 0.f;
    #pragma unroll
    for (int pl = 0; pl < 3; ++pl) {
      const float c1 = (pl == 2) ? py : px;      // xy:(x,y) xz:(x,z) yz:(y,z)
      const float c2 = (pl == 0) ? py : pz;
      const float c1f = floorf(c1), c2f = floorf(c2);
      int i1 = (int)c1f, i2 = (int)c2f;
      i1 = i1 < 0 ? 0 : (i1 > 511 ? 511 : i1);
      i2 = i2 < 0 ? 0 : (i2 > 511 ? 511 : i2);
      const uint2 q = vp[pl * PLANE_ELEMS + i1 * 512 + i2];  // one 8B gather
      const float bl = asf(q.x << 16), br = asf(q.x & 0xffff0000u);
      const float tl = asf(q.y << 16), tr = asf(q.y & 0xffff0000u);
      const float hh = c1 - c1f, vv = c2 - c2f;
      const float bot = fmaf(br - bl, hh, bl);
      const float top = fmaf(tr - tl, hh, tl);
      F += fmaf(top - bot, vv, bot);
    }

    float u = (F - F_LO) * F_INVD;
    int iu = (int)floorf(u);
    iu = iu < 0 ? 0 : (iu > NT - 2 ? NT - 2 : iu);
    float fr = u - (float)iu;
    fr = fr < 0.f ? 0.f : (fr > 1.f ? 1.f : fr);
    const float2 tpair = tp[iu];
    res[s] = fmaf(tpair.y - tpair.x, fr, tpair.x);
  }

  if (i0 + 3 < n) {
    f32x4 r; r.x = res[0]; r.y = res[1]; r.z = res[2]; r.w = res[3];
    __builtin_nontemporal_store(r, (f32x4*)&out[i0]);
  } else {
    #pragma unroll
    for (int s = 0; s < 4; ++s)
      if (i0 + s < n) out[i0 + s] = res[s];
  }
}

// ================= tier2: r6's proven path =================================
__global__ __launch_bounds__(256) void neusdf_table_build(
    const float* __restrict__ w1, const float* __restrict__ b1,
    const float* __restrict__ w2, const float* __restrict__ b2,
    const float* __restrict__ w3, const float* __restrict__ b3,
    float* __restrict__ table) {
  __shared__ float part[4][64];
  const int tid = threadIdx.x, lane = tid & 63, wave = tid >> 6;
  const int entry = blockIdx.x * 64 + lane;
  const float F = F_LO + (float)entry * F_DELTA;
  const int j0 = __builtin_amdgcn_readfirstlane(wave * 32);
  float p = 0.f;
  #pragma unroll 1
  for (int j = j0; j < j0 + 32; j += 4) {
    float a0 = b2[j + 0], a1 = b2[j + 1], a2 = b2[j + 2], a3 = b2[j + 3];
    #pragma unroll 8
    for (int k = 0; k < 128; ++k) {
      const float hk = fmaxf(fmaf(F, w1[k], b1[k]), 0.f);
      const float* wrow = &w2[k * 128 + j];
      a0 = fmaf(hk, wrow[0], a0);
      a1 = fmaf(hk, wrow[1], a1);
      a2 = fmaf(hk, wrow[2], a2);
      a3 = fmaf(hk, wrow[3], a3);
    }
    p = fmaf(fmaxf(a0, 0.f), w3[j + 0], p);
    p = fmaf(fmaxf(a1, 0.f), w3[j + 1], p);
    p = fmaf(fmaxf(a2, 0.f), w3[j + 2], p);
    p = fmaf(fmaxf(a3, 0.f), w3[j + 3], p);
  }
  part[wave][lane] = p;
  __syncthreads();
  if (tid < 64)
    table[blockIdx.x * 64 + tid] =
        b3[0] + part[0][tid] + part[1][tid] + part[2][tid] + part[3][tid];
}

__device__ __forceinline__ float bilerp(const float* __restrict__ plane,
                                        float c1, float c2) {
  float c1f = floorf(c1), c2f = floorf(c2);
  int i1 = (int)c1f, i2 = (int)c2f;
  i1 = i1 < 0 ? 0 : (i1 > 511 ? 511 : i1);
  i2 = i2 < 0 ? 0 : (i2 > 511 ? 511 : i2);
  int i1c = i1 + 1 > 511 ? 511 : i1 + 1;
  int i2c = i2 + 1 > 511 ? 511 : i2 + 1;
  float bl = plane[i1  * 512 + i2 ];
  float br = plane[i1c * 512 + i2 ];
  float tl = plane[i1  * 512 + i2c];
  float tr = plane[i1c * 512 + i2c];
  float h = c1 - c1f, v = c2 - c2f;
  float top = tl + (tr - tl) * h;
  float bot = bl + (br - bl) * h;
  return bot + (top - bot) * v;
}

__global__ __launch_bounds__(256) void neusdf_table_main(
    const float* __restrict__ points,
    const float* __restrict__ xy, const float* __restrict__ yz,
    const float* __restrict__ xz,
    const float* __restrict__ table,
    float* __restrict__ out, int n) {
  const int i = blockIdx.x * blockDim.x + threadIdx.x;
  if (i >= n) return;
  const float px = (points[3 * i + 0] + 1.f) * 0.5f * 511.f;
  const float py = (points[3 * i + 1] + 1.f) * 0.5f * 511.f;
  const float pz = (points[3 * i + 2] + 1.f) * 0.5f * 511.f;
  const float F = bilerp(xy, px, py) + bilerp(xz, px, pz) + bilerp(yz, py, pz);
  float u = (F - F_LO) * F_INVD;
  int iu = (int)floorf(u);
  iu = iu < 0 ? 0 : (iu > NT - 2 ? NT - 2 : iu);
  float fr = u - (float)iu;
  fr = fr < 0.f ? 0.f : (fr > 1.f ? 1.f : fr);
  const float s0 = table[iu], s1 = table[iu + 1];
  const float s = fmaf(s1 - s0, fr, s0);
  const float e = exp2f(s * 2.885390081777927f);
  out[i] = 1.f - 2.f / (e + 1.f);
}

// ================= tier3: r5's verified direct kernel ======================
__global__ __launch_bounds__(256) void neusdf_direct_kernel(
    const float* __restrict__ points,
    const float* __restrict__ xy, const float* __restrict__ yz,
    const float* __restrict__ xz,
    const float* __restrict__ w1, const float* __restrict__ b1,
    const float* __restrict__ w2, const float* __restrict__ b2,
    const float* __restrict__ w3, const float* __restrict__ b3,
    float* __restrict__ out, int n) {
  const int i = blockIdx.x * blockDim.x + threadIdx.x;
  if (i >= n) return;
  const float px = (points[3 * i + 0] + 1.f) * 0.5f * 511.f;
  const float py = (points[3 * i + 1] + 1.f) * 0.5f * 511.f;
  const float pz = (points[3 * i + 2] + 1.f) * 0.5f * 511.f;
  const float F = bilerp(xy, px, py) + bilerp(xz, px, pz) + bilerp(yz, py, pz);
  float h[128];
  #pragma unroll
  for (int k = 0; k < 128; ++k)
    h[k] = fmaxf(fmaf(F, w1[k], b1[k]), 0.f);
  float s = b3[0];
  #pragma unroll 1
  for (int j = 0; j < 128; j += 4) {
    float a0 = b2[j + 0], a1 = b2[j + 1], a2 = b2[j + 2], a3 = b2[j + 3];
    #pragma unroll
    for (int k = 0; k < 128; ++k) {
      const float hk = h[k];
      const float* wrow = &w2[k * 128 + j];
      a0 = fmaf(hk, wrow[0], a0);
      a1 = fmaf(hk, wrow[1], a1);
      a2 = fmaf(hk, wrow[2], a2);
      a3 = fmaf(hk, wrow[3], a3);
    }
    s = fmaf(fmaxf(a0, 0.f), w3[j + 0], s);
    s = fmaf(fmaxf(a1, 0.f), w3[j + 1], s);
    s = fmaf(fmaxf(a2, 0.f), w3[j + 2], s);
    s = fmaf(fmaxf(a3, 0.f), w3[j + 3], s);
  }
  const float e = exp2f(s * 2.885390081777927f);
  out[i] = 1.f - 2.f / (e + 1.f);
}

extern "C" void kernel_launch(void* const* d_in, const int* in_sizes, int n_in,
                              void* d_out, int out_size, void* d_ws, size_t ws_size,
                              hipStream_t stream) {
  const float* points = (const float*)d_in[0];
  const float* xy = (const float*)d_in[1];
  const float* yz = (const float*)d_in[2];
  const float* xz = (const float*)d_in[3];
  const float* w1 = (const float*)d_in[4];
  const float* b1 = (const float*)d_in[5];
  const float* w2 = (const float*)d_in[6];
  const float* b2 = (const float*)d_in[7];
  const float* w3 = (const float*)d_in[8];
  const float* b3 = (const float*)d_in[9];
  int n = out_size < 1048576 ? out_size : 1048576;

  if (ws_size >= WS_NEED) {
    uint2* vp = (uint2*)d_ws;
    float2* tp = (float2*)((char*)d_ws + TP_OFF);
    neusdf_prep<<<PACK_BLOCKS + BUILD_BLOCKS, 1024, 0, stream>>>(
        xy, yz, xz, w1, b1, w2, b2, w3, b3, vp, tp);
    const int threads = (n + 3) / 4;
    NeuSDF_1743756722497_kernel<<<(threads + 255) / 256, 256, 0, stream>>>(
        points, vp, tp, (float*)d_out, n);
  } else if (ws_size >= (size_t)NT * sizeof(float)) {
    float* table = (float*)d_ws;
    neusdf_table_build<<<NT / 64, 256, 0, stream>>>(w1, b1, w2, b2, w3, b3, table);
    neusdf_table_main<<<(n + 255) / 256, 256, 0, stream>>>(
        points, xy, yz, xz, table, (float*)d_out, n);
  } else {
    neusdf_direct_kernel<<<(n + 255) / 256, 256, 0, stream>>>(
        points, xy, yz, xz, w1, b1, w2, b2, w3, b3, (float*)d_out, n);
  }
}

// Round 3
// 117.300 us; speedup vs baseline: 1.0482x; 1.0482x over previous
//
#include <hip/hip_runtime.h>
#include <stdint.h>

// NeuSDF round 12. Verified world: inputs f32, output f32, bf16-space compare
// (floor 0.002, threshold 0.0134). out = tanh(s(F)), s tabulated (NT=16384).
// History: r9 = 117.6us (vertical bf16-pair planes, 3MB, 7 gathers/pt).
// r11 quad-pack (6MB, 4 gathers/pt) REGRESSED to 123.0 -> kernel is
// cache-residency bound, not gather-issue bound: the 2 dwords/plane in r9
// already share a cache line; doubling footprint past the 4MB/XCD L2 cost
// more than the saved instructions. r12: exact r9 layout restored (3MB vp,
// no NT hints) + ONE footprint shrink: tp as packed bf16 pairs (128KB->64KB,
// hot +-7sigma region ~23KB -> fits 32KB L1; final dependent gather becomes
// L1-hit). Adds <=0.002 quantization, absmax expected <=0.006 (thr 0.0134).

#define NT      16384
#define F_LO    (-20.0f)
#define F_DELTA (40.0f / (float)NT)
#define F_INVD  ((float)NT / 40.0f)

#define PLANE_ELEMS (512 * 512)
#define VP_BYTES    ((size_t)(3 * PLANE_ELEMS) * 4)   // 3 MB (vertical pairs)
#define TP_OFF      VP_BYTES
#define WS_NEED     (TP_OFF + (size_t)NT * 4)

#define PACK_BLOCKS  (3 * PLANE_ELEMS / 1024)         // 768
#define BUILD_BLOCKS ((NT - 1 + 62) / 63)             // 261

__device__ __forceinline__ uint32_t f2bfbits(float f) {  // RNE
  union { float f; uint32_t i; } x; x.f = f;
  uint32_t r = x.i + 0x7fffu + ((x.i >> 16) & 1u);
  return r >> 16;
}
__device__ __forceinline__ float asf(uint32_t u) {
  union { uint32_t i; float f; } x; x.i = u; return x.f;
}

// ---------------- tier1 prep: pack (blocks [0,768)) + build (rest) ----------
__global__ __launch_bounds__(1024) void neusdf_prep(
    const float* __restrict__ xy, const float* __restrict__ yz,
    const float* __restrict__ xz,
    const float* __restrict__ w1, const float* __restrict__ b1,
    const float* __restrict__ w2, const float* __restrict__ b2,
    const float* __restrict__ w3, const float* __restrict__ b3,
    uint32_t* __restrict__ vp, uint32_t* __restrict__ tp) {
  __shared__ float part[16][64];
  __shared__ float tv[64];
  const int tid = threadIdx.x;

  if (blockIdx.x < PACK_BLOCKS) {
    // ---- pack planes as vertical bf16 pairs:
    // vp[pl][r*512+c] = bf16(p[r][c]) | bf16(p[min(r+1,511)][c]) << 16
    const int idx = blockIdx.x * 1024 + tid;
    const int pl = idx >> 18;
    const int rc = idx & (PLANE_ELEMS - 1);
    const int r = rc >> 9, c = rc & 511;
    const float* p = (pl == 0) ? xy : ((pl == 1) ? xz : yz);
    const int r1 = r + 1 > 511 ? 511 : r + 1;
    const uint32_t lo = f2bfbits(p[r  * 512 + c]);
    const uint32_t hi = f2bfbits(p[r1 * 512 + c]);
    vp[idx] = lo | (hi << 16);
    return;
  }

  // ---- table build: 63 entries/block (overlapped so pairs are local),
  // 16 waves x 8 j-chains. h fused into k-loop (no h[] array -> no spill);
  // w2 rows via SGPR base -> s_load broadcast.
  const int lane = tid & 63, wave = tid >> 6;
  const int base = (blockIdx.x - PACK_BLOCKS) * 63;
  int entry = base + lane;
  if (entry > NT - 1) entry = NT - 1;
  const float F = F_LO + (float)entry * F_DELTA;
  const int j0 = __builtin_amdgcn_readfirstlane(wave * 8);

  float a[8];
  #pragma unroll
  for (int jj = 0; jj < 8; ++jj) a[jj] = b2[j0 + jj];
  #pragma unroll 8
  for (int k = 0; k < 128; ++k) {
    const float hk = fmaxf(fmaf(F, w1[k], b1[k]), 0.f);
    const float* wrow = &w2[k * 128 + j0];
    #pragma unroll
    for (int jj = 0; jj < 8; ++jj)
      a[jj] = fmaf(hk, wrow[jj], a[jj]);
  }
  float p = 0.f;
  #pragma unroll
  for (int jj = 0; jj < 8; ++jj)
    p = fmaf(fmaxf(a[jj], 0.f), w3[j0 + jj], p);
  part[wave][lane] = p;
  __syncthreads();

  if (tid < 64) {
    float s = b3[0];
    #pragma unroll
    for (int w = 0; w < 16; ++w) s += part[w][tid];
    const float e = exp2f(s * 2.885390081777927f);
    tv[tid] = 1.f - 2.f / (e + 1.f);          // tanh(s)
  }
  __syncthreads();
  if (tid < 63) {
    const int pi = base + tid;
    if (pi <= NT - 2)
      tp[pi] = f2bfbits(tv[tid]) | (f2bfbits(tv[tid + 1]) << 16);
  }
}

// ---------------- tier1 main: 4 pts/thread, 28 gathers in flight ------------
__global__ __launch_bounds__(256) void NeuSDF_1743756722497_kernel(
    const float* __restrict__ points,
    const uint32_t* __restrict__ vp,   // vertical bf16-pair planes: xy, xz, yz
    const uint32_t* __restrict__ tp,   // packed bf16 tanh pairs (64 KB)
    float* __restrict__ out, int n) {
  const int t = blockIdx.x * 256 + threadIdx.x;
  const int i0 = t * 4;
  if (i0 >= n) return;

  float xs[4], ys[4], zs[4];
  if (i0 + 3 < n) {
    const float4* p4 = (const float4*)(points + (size_t)i0 * 3);  // 16B aligned
    const float4 a = p4[0], b = p4[1], c = p4[2];
    xs[0] = a.x; ys[0] = a.y; zs[0] = a.z;
    xs[1] = a.w; ys[1] = b.x; zs[1] = b.y;
    xs[2] = b.z; ys[2] = b.w; zs[2] = c.x;
    xs[3] = c.y; ys[3] = c.z; zs[3] = c.w;
  } else {
    #pragma unroll
    for (int s = 0; s < 4; ++s) {
      const int i = i0 + s < n ? i0 + s : n - 1;
      xs[s] = points[3 * i + 0]; ys[s] = points[3 * i + 1]; zs[s] = points[3 * i + 2];
    }
  }

  float res[4];
  #pragma unroll
  for (int s = 0; s < 4; ++s) {
    const float px = (xs[s] + 1.f) * 0.5f * 511.f;
    const float py = (ys[s] + 1.f) * 0.5f * 511.f;
    const float pz = (zs[s] + 1.f) * 0.5f * 511.f;

    float F = 0.f;
    #pragma unroll
    for (int pl = 0; pl < 3; ++pl) {
      const float c1 = (pl == 2) ? py : px;      // xy:(x,y) xz:(x,z) yz:(y,z)
      const float c2 = (pl == 0) ? py : pz;
      const float c1f = floorf(c1), c2f = floorf(c2);
      int i1 = (int)c1f, i2 = (int)c2f;
      i1 = i1 < 0 ? 0 : (i1 > 511 ? 511 : i1);
      i2 = i2 < 0 ? 0 : (i2 > 511 ? 511 : i2);
      const int i2c = i2 + 1 > 511 ? 511 : i2 + 1;
      const uint32_t* rowp = vp + pl * PLANE_ELEMS + i1 * 512;
      const uint32_t u1 = rowp[i2];              // (bl, br)
      const uint32_t u2 = rowp[i2c];             // (tl, tr)
      const float bl = asf(u1 << 16), br = asf(u1 & 0xffff0000u);
      const float tl = asf(u2 << 16), tr = asf(u2 & 0xffff0000u);
      const float hh = c1 - c1f, vv = c2 - c2f;
      const float bot = fmaf(br - bl, hh, bl);
      const float top = fmaf(tr - tl, hh, tl);
      F += fmaf(top - bot, vv, bot);
    }

    float u = (F - F_LO) * F_INVD;
    int iu = (int)floorf(u);
    iu = iu < 0 ? 0 : (iu > NT - 2 ? NT - 2 : iu);
    float fr = u - (float)iu;
    fr = fr < 0.f ? 0.f : (fr > 1.f ? 1.f : fr);
    const uint32_t tpair = tp[iu];               // 4B L1-hot gather
    const float t0 = asf(tpair << 16), t1 = asf(tpair & 0xffff0000u);
    res[s] = fmaf(t1 - t0, fr, t0);
  }

  if (i0 + 3 < n) {
    *(float4*)&out[i0] = make_float4(res[0], res[1], res[2], res[3]);
  } else {
    #pragma unroll
    for (int s = 0; s < 4; ++s)
      if (i0 + s < n) out[i0 + s] = res[s];
  }
}

// ================= tier2: r6's proven path =================================
__global__ __launch_bounds__(256) void neusdf_table_build(
    const float* __restrict__ w1, const float* __restrict__ b1,
    const float* __restrict__ w2, const float* __restrict__ b2,
    const float* __restrict__ w3, const float* __restrict__ b3,
    float* __restrict__ table) {
  __shared__ float part[4][64];
  const int tid = threadIdx.x, lane = tid & 63, wave = tid >> 6;
  const int entry = blockIdx.x * 64 + lane;
  const float F = F_LO + (float)entry * F_DELTA;
  const int j0 = __builtin_amdgcn_readfirstlane(wave * 32);
  float p = 0.f;
  #pragma unroll 1
  for (int j = j0; j < j0 + 32; j += 4) {
    float a0 = b2[j + 0], a1 = b2[j + 1], a2 = b2[j + 2], a3 = b2[j + 3];
    #pragma unroll 8
    for (int k = 0; k < 128; ++k) {
      const float hk = fmaxf(fmaf(F, w1[k], b1[k]), 0.f);
      const float* wrow = &w2[k * 128 + j];
      a0 = fmaf(hk, wrow[0], a0);
      a1 = fmaf(hk, wrow[1], a1);
      a2 = fmaf(hk, wrow[2], a2);
      a3 = fmaf(hk, wrow[3], a3);
    }
    p = fmaf(fmaxf(a0, 0.f), w3[j + 0], p);
    p = fmaf(fmaxf(a1, 0.f), w3[j + 1], p);
    p = fmaf(fmaxf(a2, 0.f), w3[j + 2], p);
    p = fmaf(fmaxf(a3, 0.f), w3[j + 3], p);
  }
  part[wave][lane] = p;
  __syncthreads();
  if (tid < 64)
    table[blockIdx.x * 64 + tid] =
        b3[0] + part[0][tid] + part[1][tid] + part[2][tid] + part[3][tid];
}

__device__ __forceinline__ float bilerp(const float* __restrict__ plane,
                                        float c1, float c2) {
  float c1f = floorf(c1), c2f = floorf(c2);
  int i1 = (int)c1f, i2 = (int)c2f;
  i1 = i1 < 0 ? 0 : (i1 > 511 ? 511 : i1);
  i2 = i2 < 0 ? 0 : (i2 > 511 ? 511 : i2);
  int i1c = i1 + 1 > 511 ? 511 : i1 + 1;
  int i2c = i2 + 1 > 511 ? 511 : i2 + 1;
  float bl = plane[i1  * 512 + i2 ];
  float br = plane[i1c * 512 + i2 ];
  float tl = plane[i1  * 512 + i2c];
  float tr = plane[i1c * 512 + i2c];
  float h = c1 - c1f, v = c2 - c2f;
  float top = tl + (tr - tl) * h;
  float bot = bl + (br - bl) * h;
  return bot + (top - bot) * v;
}

__global__ __launch_bounds__(256) void neusdf_table_main(
    const float* __restrict__ points,
    const float* __restrict__ xy, const float* __restrict__ yz,
    const float* __restrict__ xz,
    const float* __restrict__ table,
    float* __restrict__ out, int n) {
  const int i = blockIdx.x * blockDim.x + threadIdx.x;
  if (i >= n) return;
  const float px = (points[3 * i + 0] + 1.f) * 0.5f * 511.f;
  const float py = (points[3 * i + 1] + 1.f) * 0.5f * 511.f;
  const float pz = (points[3 * i + 2] + 1.f) * 0.5f * 511.f;
  const float F = bilerp(xy, px, py) + bilerp(xz, px, pz) + bilerp(yz, py, pz);
  float u = (F - F_LO) * F_INVD;
  int iu = (int)floorf(u);
  iu = iu < 0 ? 0 : (iu > NT - 2 ? NT - 2 : iu);
  float fr = u - (float)iu;
  fr = fr < 0.f ? 0.f : (fr > 1.f ? 1.f : fr);
  const float s0 = table[iu], s1 = table[iu + 1];
  const float s = fmaf(s1 - s0, fr, s0);
  const float e = exp2f(s * 2.885390081777927f);
  out[i] = 1.f - 2.f / (e + 1.f);
}

// ================= tier3: r5's verified direct kernel ======================
__global__ __launch_bounds__(256) void neusdf_direct_kernel(
    const float* __restrict__ points,
    const float* __restrict__ xy, const float* __restrict__ yz,
    const float* __restrict__ xz,
    const float* __restrict__ w1, const float* __restrict__ b1,
    const float* __restrict__ w2, const float* __restrict__ b2,
    const float* __restrict__ w3, const float* __restrict__ b3,
    float* __restrict__ out, int n) {
  const int i = blockIdx.x * blockDim.x + threadIdx.x;
  if (i >= n) return;
  const float px = (points[3 * i + 0] + 1.f) * 0.5f * 511.f;
  const float py = (points[3 * i + 1] + 1.f) * 0.5f * 511.f;
  const float pz = (points[3 * i + 2] + 1.f) * 0.5f * 511.f;
  const float F = bilerp(xy, px, py) + bilerp(xz, px, pz) + bilerp(yz, py, pz);
  float h[128];
  #pragma unroll
  for (int k = 0; k < 128; ++k)
    h[k] = fmaxf(fmaf(F, w1[k], b1[k]), 0.f);
  float s = b3[0];
  #pragma unroll 1
  for (int j = 0; j < 128; j += 4) {
    float a0 = b2[j + 0], a1 = b2[j + 1], a2 = b2[j + 2], a3 = b2[j + 3];
    #pragma unroll
    for (int k = 0; k < 128; ++k) {
      const float hk = h[k];
      const float* wrow = &w2[k * 128 + j];
      a0 = fmaf(hk, wrow[0], a0);
      a1 = fmaf(hk, wrow[1], a1);
      a2 = fmaf(hk, wrow[2], a2);
      a3 = fmaf(hk, wrow[3], a3);
    }
    s = fmaf(fmaxf(a0, 0.f), w3[j + 0], s);
    s = fmaf(fmaxf(a1, 0.f), w3[j + 1], s);
    s = fmaf(fmaxf(a2, 0.f), w3[j + 2], s);
    s = fmaf(fmaxf(a3, 0.f), w3[j + 3], s);
  }
  const float e = exp2f(s * 2.885390081777927f);
  out[i] = 1.f - 2.f / (e + 1.f);
}

extern "C" void kernel_launch(void* const* d_in, const int* in_sizes, int n_in,
                              void* d_out, int out_size, void* d_ws, size_t ws_size,
                              hipStream_t stream) {
  const float* points = (const float*)d_in[0];
  const float* xy = (const float*)d_in[1];
  const float* yz = (const float*)d_in[2];
  const float* xz = (const float*)d_in[3];
  const float* w1 = (const float*)d_in[4];
  const float* b1 = (const float*)d_in[5];
  const float* w2 = (const float*)d_in[6];
  const float* b2 = (const float*)d_in[7];
  const float* w3 = (const float*)d_in[8];
  const float* b3 = (const float*)d_in[9];
  int n = out_size < 1048576 ? out_size : 1048576;

  if (ws_size >= WS_NEED) {
    uint32_t* vp = (uint32_t*)d_ws;
    uint32_t* tp = (uint32_t*)((char*)d_ws + TP_OFF);
    neusdf_prep<<<PACK_BLOCKS + BUILD_BLOCKS, 1024, 0, stream>>>(
        xy, yz, xz, w1, b1, w2, b2, w3, b3, vp, tp);
    const int threads = (n + 3) / 4;
    NeuSDF_1743756722497_kernel<<<(threads + 255) / 256, 256, 0, stream>>>(
        points, vp, tp, (float*)d_out, n);
  } else if (ws_size >= (size_t)NT * sizeof(float)) {
    float* table = (float*)d_ws;
    neusdf_table_build<<<NT / 64, 256, 0, stream>>>(w1, b1, w2, b2, w3, b3, table);
    neusdf_table_main<<<(n + 255) / 256, 256, 0, stream>>>(
        points, xy, yz, xz, table, (float*)d_out, n);
  } else {
    neusdf_direct_kernel<<<(n + 255) / 256, 256, 0, stream>>>(
        points, xy, yz, xz, w1, b1, w2, b2, w3, b3, (float*)d_out, n);
  }
}

// Round 4
// 114.892 us; speedup vs baseline: 1.0702x; 1.0210x over previous
//
#include <hip/hip_runtime.h>
#include <stdint.h>

// NeuSDF round 13. Verified world: inputs f32, output f32, bf16-space compare
// (floor 0.002, threshold 0.0134). out = tanh(s(F)), s tabulated (NT=16384).
// ACCOUNTING (r12): dur_us includes ~88us of harness ws-poison fills (2x44us,
// 256MiB each; both our kernels are <43.5us since only fills show in top-5).
// Controllable slice: prep ~8-12us, main ~17-22us, gaps ~2-4us.
// History: r9/r12 = 117.3-117.6us (vertical bf16-pair planes 3MB, 7 gathers/pt,
// bf16 tp 64KB). r11 quad-pack 6MB REGRESSED (+5.4 total = +30% on main):
// cache-residency bound, not gather-issue bound. r12 L1-hot table: neutral.
// r13 experiment (single variable): main at 2 pts/thread instead of 4 ->
// 8192 waves = 32 waves/CU (was 16, grid-limited) + __launch_bounds__(256,8)
// to cap VGPR at 64. Tests "main is latency-bound on the 2-level dependent
// gather chain" — doubled wave count interleaves chains better; total
// in-flight gathers/CU unchanged.

#define NT      16384
#define F_LO    (-20.0f)
#define F_DELTA (40.0f / (float)NT)
#define F_INVD  ((float)NT / 40.0f)

#define PLANE_ELEMS (512 * 512)
#define VP_BYTES    ((size_t)(3 * PLANE_ELEMS) * 4)   // 3 MB (vertical pairs)
#define TP_OFF      VP_BYTES
#define WS_NEED     (TP_OFF + (size_t)NT * 4)

#define PACK_BLOCKS  (3 * PLANE_ELEMS / 1024)         // 768
#define BUILD_BLOCKS ((NT - 1 + 62) / 63)             // 261

__device__ __forceinline__ uint32_t f2bfbits(float f) {  // RNE
  union { float f; uint32_t i; } x; x.f = f;
  uint32_t r = x.i + 0x7fffu + ((x.i >> 16) & 1u);
  return r >> 16;
}
__device__ __forceinline__ float asf(uint32_t u) {
  union { uint32_t i; float f; } x; x.i = u; return x.f;
}

// ---------------- tier1 prep: pack (blocks [0,768)) + build (rest) ----------
__global__ __launch_bounds__(1024) void neusdf_prep(
    const float* __restrict__ xy, const float* __restrict__ yz,
    const float* __restrict__ xz,
    const float* __restrict__ w1, const float* __restrict__ b1,
    const float* __restrict__ w2, const float* __restrict__ b2,
    const float* __restrict__ w3, const float* __restrict__ b3,
    uint32_t* __restrict__ vp, uint32_t* __restrict__ tp) {
  __shared__ float part[16][64];
  __shared__ float tv[64];
  const int tid = threadIdx.x;

  if (blockIdx.x < PACK_BLOCKS) {
    // ---- pack planes as vertical bf16 pairs:
    // vp[pl][r*512+c] = bf16(p[r][c]) | bf16(p[min(r+1,511)][c]) << 16
    const int idx = blockIdx.x * 1024 + tid;
    const int pl = idx >> 18;
    const int rc = idx & (PLANE_ELEMS - 1);
    const int r = rc >> 9, c = rc & 511;
    const float* p = (pl == 0) ? xy : ((pl == 1) ? xz : yz);
    const int r1 = r + 1 > 511 ? 511 : r + 1;
    const uint32_t lo = f2bfbits(p[r  * 512 + c]);
    const uint32_t hi = f2bfbits(p[r1 * 512 + c]);
    vp[idx] = lo | (hi << 16);
    return;
  }

  // ---- table build: 63 entries/block (overlapped so pairs are local),
  // 16 waves x 8 j-chains. h fused into k-loop (no h[] array -> no spill);
  // w2 rows via SGPR base -> s_load broadcast.
  const int lane = tid & 63, wave = tid >> 6;
  const int base = (blockIdx.x - PACK_BLOCKS) * 63;
  int entry = base + lane;
  if (entry > NT - 1) entry = NT - 1;
  const float F = F_LO + (float)entry * F_DELTA;
  const int j0 = __builtin_amdgcn_readfirstlane(wave * 8);

  float a[8];
  #pragma unroll
  for (int jj = 0; jj < 8; ++jj) a[jj] = b2[j0 + jj];
  #pragma unroll 8
  for (int k = 0; k < 128; ++k) {
    const float hk = fmaxf(fmaf(F, w1[k], b1[k]), 0.f);
    const float* wrow = &w2[k * 128 + j0];
    #pragma unroll
    for (int jj = 0; jj < 8; ++jj)
      a[jj] = fmaf(hk, wrow[jj], a[jj]);
  }
  float p = 0.f;
  #pragma unroll
  for (int jj = 0; jj < 8; ++jj)
    p = fmaf(fmaxf(a[jj], 0.f), w3[j0 + jj], p);
  part[wave][lane] = p;
  __syncthreads();

  if (tid < 64) {
    float s = b3[0];
    #pragma unroll
    for (int w = 0; w < 16; ++w) s += part[w][tid];
    const float e = exp2f(s * 2.885390081777927f);
    tv[tid] = 1.f - 2.f / (e + 1.f);          // tanh(s)
  }
  __syncthreads();
  if (tid < 63) {
    const int pi = base + tid;
    if (pi <= NT - 2)
      tp[pi] = f2bfbits(tv[tid]) | (f2bfbits(tv[tid + 1]) << 16);
  }
}

// ---------------- tier1 main: 2 pts/thread, full 32-wave/CU occupancy -------
__global__ __launch_bounds__(256, 8) void NeuSDF_1743756722497_kernel(
    const float* __restrict__ points,
    const uint32_t* __restrict__ vp,   // vertical bf16-pair planes: xy, xz, yz
    const uint32_t* __restrict__ tp,   // packed bf16 tanh pairs (64 KB)
    float* __restrict__ out, int n) {
  const int t = blockIdx.x * 256 + threadIdx.x;
  const int i0 = t * 2;
  if (i0 >= n) return;

  float xs[2], ys[2], zs[2];
  if (i0 + 1 < n) {
    // 6 consecutive floats at points+i0*3 (byte offset i0*12, 8B-aligned)
    const float2* p2 = (const float2*)(points + (size_t)i0 * 3);
    const float2 a = p2[0], b = p2[1], c = p2[2];
    xs[0] = a.x; ys[0] = a.y; zs[0] = b.x;
    xs[1] = b.y; ys[1] = c.x; zs[1] = c.y;
  } else {
    #pragma unroll
    for (int s = 0; s < 2; ++s) {
      const int i = i0 + s < n ? i0 + s : n - 1;
      xs[s] = points[3 * i + 0]; ys[s] = points[3 * i + 1]; zs[s] = points[3 * i + 2];
    }
  }

  float res[2];
  #pragma unroll
  for (int s = 0; s < 2; ++s) {
    const float px = (xs[s] + 1.f) * 0.5f * 511.f;
    const float py = (ys[s] + 1.f) * 0.5f * 511.f;
    const float pz = (zs[s] + 1.f) * 0.5f * 511.f;

    float F = 0.f;
    #pragma unroll
    for (int pl = 0; pl < 3; ++pl) {
      const float c1 = (pl == 2) ? py : px;      // xy:(x,y) xz:(x,z) yz:(y,z)
      const float c2 = (pl == 0) ? py : pz;
      const float c1f = floorf(c1), c2f = floorf(c2);
      int i1 = (int)c1f, i2 = (int)c2f;
      i1 = i1 < 0 ? 0 : (i1 > 511 ? 511 : i1);
      i2 = i2 < 0 ? 0 : (i2 > 511 ? 511 : i2);
      const int i2c = i2 + 1 > 511 ? 511 : i2 + 1;
      const uint32_t* rowp = vp + pl * PLANE_ELEMS + i1 * 512;
      const uint32_t u1 = rowp[i2];              // (bl, br)
      const uint32_t u2 = rowp[i2c];             // (tl, tr)
      const float bl = asf(u1 << 16), br = asf(u1 & 0xffff0000u);
      const float tl = asf(u2 << 16), tr = asf(u2 & 0xffff0000u);
      const float hh = c1 - c1f, vv = c2 - c2f;
      const float bot = fmaf(br - bl, hh, bl);
      const float top = fmaf(tr - tl, hh, tl);
      F += fmaf(top - bot, vv, bot);
    }

    float u = (F - F_LO) * F_INVD;
    int iu = (int)floorf(u);
    iu = iu < 0 ? 0 : (iu > NT - 2 ? NT - 2 : iu);
    float fr = u - (float)iu;
    fr = fr < 0.f ? 0.f : (fr > 1.f ? 1.f : fr);
    const uint32_t tpair = tp[iu];               // 4B gather (L1/L2-hot)
    const float t0 = asf(tpair << 16), t1 = asf(tpair & 0xffff0000u);
    res[s] = fmaf(t1 - t0, fr, t0);
  }

  if (i0 + 1 < n) {
    *(float2*)&out[i0] = make_float2(res[0], res[1]);
  } else {
    out[i0] = res[0];
  }
}

// ================= tier2: r6's proven path =================================
__global__ __launch_bounds__(256) void neusdf_table_build(
    const float* __restrict__ w1, const float* __restrict__ b1,
    const float* __restrict__ w2, const float* __restrict__ b2,
    const float* __restrict__ w3, const float* __restrict__ b3,
    float* __restrict__ table) {
  __shared__ float part[4][64];
  const int tid = threadIdx.x, lane = tid & 63, wave = tid >> 6;
  const int entry = blockIdx.x * 64 + lane;
  const float F = F_LO + (float)entry * F_DELTA;
  const int j0 = __builtin_amdgcn_readfirstlane(wave * 32);
  float p = 0.f;
  #pragma unroll 1
  for (int j = j0; j < j0 + 32; j += 4) {
    float a0 = b2[j + 0], a1 = b2[j + 1], a2 = b2[j + 2], a3 = b2[j + 3];
    #pragma unroll 8
    for (int k = 0; k < 128; ++k) {
      const float hk = fmaxf(fmaf(F, w1[k], b1[k]), 0.f);
      const float* wrow = &w2[k * 128 + j];
      a0 = fmaf(hk, wrow[0], a0);
      a1 = fmaf(hk, wrow[1], a1);
      a2 = fmaf(hk, wrow[2], a2);
      a3 = fmaf(hk, wrow[3], a3);
    }
    p = fmaf(fmaxf(a0, 0.f), w3[j + 0], p);
    p = fmaf(fmaxf(a1, 0.f), w3[j + 1], p);
    p = fmaf(fmaxf(a2, 0.f), w3[j + 2], p);
    p = fmaf(fmaxf(a3, 0.f), w3[j + 3], p);
  }
  part[wave][lane] = p;
  __syncthreads();
  if (tid < 64)
    table[blockIdx.x * 64 + tid] =
        b3[0] + part[0][tid] + part[1][tid] + part[2][tid] + part[3][tid];
}

__device__ __forceinline__ float bilerp(const float* __restrict__ plane,
                                        float c1, float c2) {
  float c1f = floorf(c1), c2f = floorf(c2);
  int i1 = (int)c1f, i2 = (int)c2f;
  i1 = i1 < 0 ? 0 : (i1 > 511 ? 511 : i1);
  i2 = i2 < 0 ? 0 : (i2 > 511 ? 511 : i2);
  int i1c = i1 + 1 > 511 ? 511 : i1 + 1;
  int i2c = i2 + 1 > 511 ? 511 : i2 + 1;
  float bl = plane[i1  * 512 + i2 ];
  float br = plane[i1c * 512 + i2 ];
  float tl = plane[i1  * 512 + i2c];
  float tr = plane[i1c * 512 + i2c];
  float h = c1 - c1f, v = c2 - c2f;
  float top = tl + (tr - tl) * h;
  float bot = bl + (br - bl) * h;
  return bot + (top - bot) * v;
}

__global__ __launch_bounds__(256) void neusdf_table_main(
    const float* __restrict__ points,
    const float* __restrict__ xy, const float* __restrict__ yz,
    const float* __restrict__ xz,
    const float* __restrict__ table,
    float* __restrict__ out, int n) {
  const int i = blockIdx.x * blockDim.x + threadIdx.x;
  if (i >= n) return;
  const float px = (points[3 * i + 0] + 1.f) * 0.5f * 511.f;
  const float py = (points[3 * i + 1] + 1.f) * 0.5f * 511.f;
  const float pz = (points[3 * i + 2] + 1.f) * 0.5f * 511.f;
  const float F = bilerp(xy, px, py) + bilerp(xz, px, pz) + bilerp(yz, py, pz);
  float u = (F - F_LO) * F_INVD;
  int iu = (int)floorf(u);
  iu = iu < 0 ? 0 : (iu > NT - 2 ? NT - 2 : iu);
  float fr = u - (float)iu;
  fr = fr < 0.f ? 0.f : (fr > 1.f ? 1.f : fr);
  const float s0 = table[iu], s1 = table[iu + 1];
  const float s = fmaf(s1 - s0, fr, s0);
  const float e = exp2f(s * 2.885390081777927f);
  out[i] = 1.f - 2.f / (e + 1.f);
}

// ================= tier3: r5's verified direct kernel ======================
__global__ __launch_bounds__(256) void neusdf_direct_kernel(
    const float* __restrict__ points,
    const float* __restrict__ xy, const float* __restrict__ yz,
    const float* __restrict__ xz,
    const float* __restrict__ w1, const float* __restrict__ b1,
    const float* __restrict__ w2, const float* __restrict__ b2,
    const float* __restrict__ w3, const float* __restrict__ b3,
    float* __restrict__ out, int n) {
  const int i = blockIdx.x * blockDim.x + threadIdx.x;
  if (i >= n) return;
  const float px = (points[3 * i + 0] + 1.f) * 0.5f * 511.f;
  const float py = (points[3 * i + 1] + 1.f) * 0.5f * 511.f;
  const float pz = (points[3 * i + 2] + 1.f) * 0.5f * 511.f;
  const float F = bilerp(xy, px, py) + bilerp(xz, px, pz) + bilerp(yz, py, pz);
  float h[128];
  #pragma unroll
  for (int k = 0; k < 128; ++k)
    h[k] = fmaxf(fmaf(F, w1[k], b1[k]), 0.f);
  float s = b3[0];
  #pragma unroll 1
  for (int j = 0; j < 128; j += 4) {
    float a0 = b2[j + 0], a1 = b2[j + 1], a2 = b2[j + 2], a3 = b2[j + 3];
    #pragma unroll
    for (int k = 0; k < 128; ++k) {
      const float hk = h[k];
      const float* wrow = &w2[k * 128 + j];
      a0 = fmaf(hk, wrow[0], a0);
      a1 = fmaf(hk, wrow[1], a1);
      a2 = fmaf(hk, wrow[2], a2);
      a3 = fmaf(hk, wrow[3], a3);
    }
    s = fmaf(fmaxf(a0, 0.f), w3[j + 0], s);
    s = fmaf(fmaxf(a1, 0.f), w3[j + 1], s);
    s = fmaf(fmaxf(a2, 0.f), w3[j + 2], s);
    s = fmaf(fmaxf(a3, 0.f), w3[j + 3], s);
  }
  const float e = exp2f(s * 2.885390081777927f);
  out[i] = 1.f - 2.f / (e + 1.f);
}

extern "C" void kernel_launch(void* const* d_in, const int* in_sizes, int n_in,
                              void* d_out, int out_size, void* d_ws, size_t ws_size,
                              hipStream_t stream) {
  const float* points = (const float*)d_in[0];
  const float* xy = (const float*)d_in[1];
  const float* yz = (const float*)d_in[2];
  const float* xz = (const float*)d_in[3];
  const float* w1 = (const float*)d_in[4];
  const float* b1 = (const float*)d_in[5];
  const float* w2 = (const float*)d_in[6];
  const float* b2 = (const float*)d_in[7];
  const float* w3 = (const float*)d_in[8];
  const float* b3 = (const float*)d_in[9];
  int n = out_size < 1048576 ? out_size : 1048576;

  if (ws_size >= WS_NEED) {
    uint32_t* vp = (uint32_t*)d_ws;
    uint32_t* tp = (uint32_t*)((char*)d_ws + TP_OFF);
    neusdf_prep<<<PACK_BLOCKS + BUILD_BLOCKS, 1024, 0, stream>>>(
        xy, yz, xz, w1, b1, w2, b2, w3, b3, vp, tp);
    const int threads = (n + 1) / 2;
    NeuSDF_1743756722497_kernel<<<(threads + 255) / 256, 256, 0, stream>>>(
        points, vp, tp, (float*)d_out, n);
  } else if (ws_size >= (size_t)NT * sizeof(float)) {
    float* table = (float*)d_ws;
    neusdf_table_build<<<NT / 64, 256, 0, stream>>>(w1, b1, w2, b2, w3, b3, table);
    neusdf_table_main<<<(n + 255) / 256, 256, 0, stream>>>(
        points, xy, yz, xz, table, (float*)d_out, n);
  } else {
    neusdf_direct_kernel<<<(n + 255) / 256, 256, 0, stream>>>(
        points, xy, yz, xz, w1, b1, w2, b2, w3, b3, (float*)d_out, n);
  }
}